// Round 8
// baseline (589.634 us; speedup 1.0000x reference)
//
#include <hip/hip_runtime.h>
#include <hip/hip_bf16.h>

#define LF 64
#define NBAGS 5
#define BROWS 2048
#define OUTC 320
#define KC 2048
#define NMT 16
#define NCHUNKS 90                 // bags 1..4: 30 + 1 + 49 + 10
#define NSLOTS 178                 // 4KB windows/row: 59 + 1 + 98 + 20

#define WS_HEAD 65536
#define WP_BYTES 23068672ull       // 2816 tiles * 8192 B
#define BM_OFF (WS_HEAD + WP_BYTES)
#define BM_BYTES 47185920ull       // 90 chunks * 2048 rows * 256 B
#define PART_OFF (BM_OFF + BM_BYTES)
#define PART_BYTES 47185920ull     // 90 * 2048 * 64 * 4

typedef __attribute__((ext_vector_type(8))) short short8;
typedef __attribute__((ext_vector_type(4))) float f32x4;

struct BagArgs {
    const int*   A[NBAGS];
    const float* W[NBAGS];
    int K[NBAGS];
    int cstart[NBAGS + 1];   // KC-chunk prefix, bags 1..4
    int tstart[NBAGS + 1];   // 64-k tile prefix, all bags
};

__device__ __forceinline__ unsigned short f2bf(float f) {
    unsigned u = __float_as_uint(f);
    u += 0x7FFFu + ((u >> 16) & 1u);   // round-to-nearest-even
    return (unsigned short)(u >> 16);
}

// Pack W (f32 [K][64]) -> bf16 tiles of 64 k (8 KB), permuted so the B
// fragment matches A frags where lane (fr,kg), frag m holds k=kg*16+m*8+[0,8).
// k -> block = ((k>>3)&1)*4 + (k>>4);  short idx = (block*64 + c)*8 + (k&7).
// Zero-filled past K.  [validated R5-R7]
__global__ __launch_bounds__(256) void pack_w(BagArgs args,
                                              unsigned short* __restrict__ Wp) {
    __shared__ unsigned short ls[4][4096];
    const int wv = threadIdx.x >> 6;
    const int c  = threadIdx.x & 63;
    const int gtile = blockIdx.x * 4 + wv;

    int bag = 0;
#pragma unroll
    for (int b = 1; b < NBAGS; ++b)
        if (gtile >= args.tstart[b]) bag = b;
    const int lt = gtile - args.tstart[bag];
    const float* __restrict__ W = args.W[bag];
    const int K = args.K[bag];

    unsigned short* L = ls[wv];
#pragma unroll 8
    for (int k = 0; k < 64; ++k) {
        const int gk = lt * 64 + k;
        float v = (gk < K) ? W[(size_t)gk * LF + c] : 0.f;
        const int block = ((k >> 3) & 1) * 4 + (k >> 4);
        L[(block * LF + c) * 8 + (k & 7)] = f2bf(v);
    }
    __syncthreads();
    unsigned short* dst = Wp + ((size_t)gtile << 12);
#pragma unroll
    for (int j = 0; j < 8; ++j)
        *(short8*)(dst + c * 8 + j * 512) = *(const short8*)(L + c * 8 + j * 512);
}

// Pass 1: copy-shaped. Each wave reads 4 KB SEQUENTIAL from one row (one
// 1024-k window), emits 128 B of bitmask in the GEMM's EXACT consumption
// layout, plus one exact int popcount atomic per row.
// bm layout: tile(g, mt, wv) of 8 KB at ((g*16+mt)*4+wv)*8192; within tile:
//   byte = ss*256 + (kg*16 + fr)*4 + rs*2, u16 bit j <-> k = ss*64+kg*16+j,
//   row = mt*128 + wv*32 + rs*16 + fr.
__global__ __launch_bounds__(256) void compress(BagArgs args,
                                                unsigned char* __restrict__ bm,
                                                int* __restrict__ sums) {
    const int cwv  = threadIdx.x >> 6;
    const int lane = threadIdx.x & 63;
    const int slot = blockIdx.x * 4 + cwv;
    if (slot >= NSLOTS) return;
    int bag, s0;
    if      (slot >= 158) { bag = 4; s0 = 158; }
    else if (slot >=  60) { bag = 3; s0 = 60;  }
    else if (slot >=  59) { bag = 2; s0 = 59;  }
    else                  { bag = 1; s0 = 0;   }
    const int w   = slot - s0;
    const int row = blockIdx.y;
    const int K   = args.K[bag];
    const int* __restrict__ A = args.A[bag] + (size_t)row * K + w * 1024;

    const int fr = row & 15, rs = (row >> 4) & 1;
    const int wv = (row >> 5) & 3, mt = row >> 7;
    const int g  = args.cstart[bag] + (w >> 1);
    unsigned char* __restrict__ tile =
        bm + ((size_t)((g * 16 + mt) * 4 + wv) << 13);

    // load the whole 4 KB window first (4 dwordx4 in flight)
    int4 vv[4];
#pragma unroll
    for (int s = 0; s < 4; ++s) {
        const int k = w * 1024 + s * 256 + lane * 4;
        vv[s] = make_int4(0, 0, 0, 0);
        if (k < K) vv[s] = *(const int4*)(A + s * 256 + lane * 4);
    }

    int cnt = 0;
    const int ssb = (w & 1) * 16;
#pragma unroll
    for (int s = 0; s < 4; ++s) {
        const int4 v = vv[s];
        cnt += v.x + v.y + v.z + v.w;            // ints are exactly {0,1}
        int u = (v.x | (v.y << 1) | (v.z << 2) | (v.w << 3)) << ((lane & 3) * 4);
        u |= __shfl_xor(u, 1);
        u |= __shfl_xor(u, 2);                   // u16 for (ss, kg) in 4-lane group
        if ((lane & 3) == 0) {
            const int ss = ssb + s * 4 + (lane >> 4);
            const int kg = (lane >> 2) & 3;
            *(unsigned short*)(tile + ss * 256 + (kg * 16 + fr) * 4 + rs * 2) =
                (unsigned short)u;
        }
    }
    cnt += __shfl_xor(cnt, 1);
    cnt += __shfl_xor(cnt, 2);
    cnt += __shfl_xor(cnt, 4);
    cnt += __shfl_xor(cnt, 8);
    cnt += __shfl_xor(cnt, 16);
    cnt += __shfl_xor(cnt, 32);
    if (lane == 0) atomicAdd(&sums[bag * BROWS + row], cnt);
}

// Pass 2: MFMA GEMM off the linear bitmask. A = ONE coalesced dword per
// lane per superstep (wave: 256 B contiguous, L3-resident); B = packed Wp
// fragments (L2). R4's validated ping-pong + sched_barrier; no LDS/barriers.
__global__ __launch_bounds__(256) void bag_gemm(BagArgs args,
                                                const unsigned short* __restrict__ Wp,
                                                const unsigned char* __restrict__ bm,
                                                float* __restrict__ part)
{
    const int tid  = threadIdx.x;
    const int wave = tid >> 6;
    const int lane = tid & 63;
    const int fr   = lane & 15;
    const int kg   = lane >> 4;

    const int g  = blockIdx.x >> 4;
    const int mt = blockIdx.x & 15;

    int bag = 1;
#pragma unroll
    for (int b = 2; b < NBAGS; ++b)
        if (g >= args.cstart[b]) bag = b;
    const int chunk  = g - args.cstart[bag];
    const int K      = args.K[bag];
    const int kc0    = chunk * KC;
    const int nsuper = (min(kc0 + KC, K) - kc0 + 63) >> 6;

    const int row0 = mt * 128 + wave * 32;
    const unsigned char* __restrict__ pA =
        bm + ((size_t)((g * 16 + mt) * 4 + wave) << 13) + (kg * 16 + fr) * 4;
    const unsigned short* __restrict__ pB =
        Wp + ((size_t)(args.tstart[bag] + chunk * (KC / 64)) << 12) + (kg * LF + fr) * 8;

    f32x4 acc0[4], acc1[4];
#pragma unroll
    for (int i = 0; i < 4; ++i) {
        acc0[i] = (f32x4){0.f, 0.f, 0.f, 0.f};
        acc1[i] = (f32x4){0.f, 0.f, 0.f, 0.f};
    }

    auto loadA = [&](int ss, unsigned& x) {
        x = *(const unsigned*)(pA + ss * 256);   // rs0 bits | rs1 bits << 16
    };
    auto loadB = [&](int ss, short8 (&y)[2][4]) {
        const unsigned short* p = pB + (size_t)ss * 4096;
#pragma unroll
        for (int m = 0; m < 2; ++m)
#pragma unroll
            for (int ni = 0; ni < 4; ++ni)
                y[m][ni] = *(const short8*)(p + m * 2048 + ni * 128);
    };

    // 2 bits -> dword of 2 bf16 (0x3F80 = bf16(1))   [validated R7]
    auto bf16pair = [](unsigned b) -> int {
        return (int)((b & 1u) * 0x3F80u + (b & 2u) * 0x1FC00000u);
    };
    auto mkfrag = [&](unsigned byte) -> short8 {
        int4 u = make_int4(bf16pair(byte), bf16pair(byte >> 2),
                           bf16pair(byte >> 4), bf16pair(byte >> 6));
        return *(short8*)&u;
    };
    auto compute = [&](unsigned x, const short8 (&y)[2][4]) {
#pragma unroll
        for (int m = 0; m < 2; ++m) {
            const short8 fa0 = mkfrag((x >> (m * 8)) & 0xFFu);
            const short8 fa1 = mkfrag((x >> (16 + m * 8)) & 0xFFu);
#pragma unroll
            for (int ni = 0; ni < 4; ++ni) {
                acc0[ni] = __builtin_amdgcn_mfma_f32_16x16x32_bf16(fa0, y[m][ni], acc0[ni], 0, 0, 0);
                acc1[ni] = __builtin_amdgcn_mfma_f32_16x16x32_bf16(fa1, y[m][ni], acc1[ni], 0, 0, 0);
            }
        }
    };

    unsigned Aa, Ab;
    short8 Ba[2][4], Bb[2][4];
    loadA(0, Aa);
    loadB(0, Ba);
    const int npair = (nsuper + 1) >> 1;
    for (int p = 0; p < npair; ++p) {
        const int s1  = 2 * p + 1;
        const int s1c = min(s1, nsuper - 1);
        loadA(s1c, Ab);
        loadB(s1c, Bb);
        __builtin_amdgcn_sched_barrier(0);
        compute(Aa, Ba);                        // step 2p (always valid)
        const int s2c = min(2 * p + 2, nsuper - 1);
        loadA(s2c, Aa);
        loadB(s2c, Ba);
        __builtin_amdgcn_sched_barrier(0);
        if (s1 < nsuper)                        // uniform pad guard
            compute(Ab, Bb);
    }

    // C/D: col = lane&15 (=fr), row = kg*4 + reg   [validated R1-R7]
    float* dst = part + ((size_t)g * BROWS + row0 + kg * 4) * LF + fr;
#pragma unroll
    for (int ni = 0; ni < 4; ++ni)
#pragma unroll
        for (int r = 0; r < 4; ++r) {
            dst[(size_t)(r) * LF + ni * 16]      = acc0[ni][r];
            dst[(size_t)(16 + r) * LF + ni * 16] = acc1[ni][r];
        }
}

// Sum split-K partials, normalize (incl. faithful "decades divided twice"
// bug), and compute the tiny K=12 decades bag directly in f32.
__global__ __launch_bounds__(256) void reduce_norm(BagArgs args,
                                                   const float* __restrict__ part,
                                                   float* __restrict__ out,
                                                   const int* __restrict__ sums)
{
    const int idx = blockIdx.x * 256 + threadIdx.x;
    if (idx >= BROWS * OUTC) return;
    const int row = idx / OUTC;
    const int c   = idx - row * OUTC;
    const int bag = c >> 6;
    const int col = c & 63;

    float v;
    if (bag == 0) {
        const int*   A0 = args.A[0];
        const float* W0 = args.W[0];
        float a = 0.f; int s = 0;
#pragma unroll
        for (int k = 0; k < 12; ++k) {
            const int x = A0[row * 12 + k];
            s += x;
            if (x) a += W0[k * LF + col];
        }
        if (s) a /= (float)s;
        const int sm = sums[1 * BROWS + row];   // ref bug: also divide by movie sum
        if (sm) a /= (float)sm;
        v = a;
    } else {
        float a = 0.f;
        for (int gg = args.cstart[bag]; gg < args.cstart[bag + 1]; ++gg)
            a += part[((size_t)gg * BROWS + row) * LF + col];
        v = a;
        if (bag >= 2) {
            const int s = sums[bag * BROWS + row];
            if (s) v /= (float)s;
        }
        // bag 1 (movies): never normalized (faithful to reference bug)
    }
    out[idx] = v;
}

// Correctness-only fallback (tiny ws): one thread per output element.
__global__ void naive_bag(BagArgs args, float* __restrict__ out) {
    const int row = blockIdx.x;
    const int c   = threadIdx.x;
    if (c >= OUTC) return;
    const int bag = c >> 6;
    const int col = c & 63;
    const int K = args.K[bag];
    const int* A = args.A[bag] + (size_t)row * K;
    const float* W = args.W[bag];
    float a = 0.f; int s = 0;
    for (int k = 0; k < K; ++k) {
        const int x = A[k];
        s += x;
        if (x) a += W[(size_t)k * LF + col];
    }
    if (bag != 1 && s) a /= (float)s;
    if (bag == 0) {
        const int* A1 = args.A[1] + (size_t)row * args.K[1];
        int sm = 0;
        for (int k = 0; k < args.K[1]; ++k) sm += A1[k];
        if (sm) a /= (float)sm;
    }
    out[(size_t)row * OUTC + c] = a;
}

extern "C" void kernel_launch(void* const* d_in, const int* in_sizes, int n_in,
                              void* d_out, int out_size, void* d_ws, size_t ws_size,
                              hipStream_t stream) {
    float* out = (float*)d_out;
    int* sums = (int*)d_ws;
    unsigned short* Wp = (unsigned short*)((char*)d_ws + WS_HEAD);
    unsigned char* bm  = (unsigned char*)((char*)d_ws + BM_OFF);
    float* part = (float*)((char*)d_ws + PART_OFF);

    BagArgs args;
    const int Ks[NBAGS] = {12, 60000, 32, 100000, 20000};
    int tcum = 0;
    for (int b = 0; b < NBAGS; ++b) {
        args.A[b] = (const int*)d_in[b];
        args.W[b] = (const float*)d_in[5 + b];
        args.K[b] = Ks[b];
        args.tstart[b] = tcum;
        tcum += (Ks[b] + 63) / 64;          // -> 2816
    }
    args.tstart[NBAGS] = tcum;
    args.cstart[0] = 0;
    int ccum = 0;
    for (int b = 1; b < NBAGS; ++b) {
        args.cstart[b] = ccum;
        ccum += (Ks[b] + KC - 1) / KC;      // 30 + 1 + 49 + 10 = 90
    }
    args.cstart[NBAGS] = ccum;

    const bool ok = ws_size >= PART_OFF + PART_BYTES;
    if (!ok) {
        naive_bag<<<BROWS, OUTC, 0, stream>>>(args, out);
        return;
    }

    hipMemsetAsync(sums, 0, NBAGS * BROWS * sizeof(int), stream);

    pack_w<<<tcum / 4, 256, 0, stream>>>(args, Wp);
    compress<<<dim3((NSLOTS + 3) / 4, BROWS), 256, 0, stream>>>(args, bm, sums);
    bag_gemm<<<NCHUNKS * NMT, 256, 0, stream>>>(args, Wp, bm, part);
    reduce_norm<<<(BROWS * OUTC + 255) / 256, 256, 0, stream>>>(args, part, out, sums);
}

// Round 9
// 579.335 us; speedup vs baseline: 1.0178x; 1.0178x over previous
//
#include <hip/hip_runtime.h>
#include <hip/hip_bf16.h>

#define LF 64
#define NBAGS 5
#define BROWS 2048
#define OUTC 320
#define KC 1024                    // k per block
#define NMT 16                     // m-tiles of 128 rows
#define NCHUNKS 178                // bags 1..4: 59 + 1 + 98 + 20

#define WS_HEAD 65536
#define NTILES 2864                // per-bag padded to 16-tile multiples
#define WP_BYTES ((size_t)NTILES * 8192)          // 23,461,888
#define PART_OFF (WS_HEAD + WP_BYTES)
#define PART_BYTES ((size_t)NCHUNKS * BROWS * LF * 4)   // 93,323,264

typedef __attribute__((ext_vector_type(8))) short short8;
typedef __attribute__((ext_vector_type(4))) float f32x4;

struct BagArgs {
    const int*   A[NBAGS];
    const float* W[NBAGS];
    int K[NBAGS];
    int cstart[NBAGS + 1];   // KC-chunk prefix, bags 1..4
    int tstart[NBAGS + 1];   // 64-k tile prefix (padded to 16), all bags
};

__device__ __forceinline__ unsigned short f2bf(float f) {
    unsigned u = __float_as_uint(f);
    u += 0x7FFFu + ((u >> 16) & 1u);   // round-to-nearest-even
    return (unsigned short)(u >> 16);
}

// Pack W (f32 [K][64]) -> bf16 tiles of 64 k (8 KB), permuted so the B
// fragment matches A frags where lane (fr,kg), frag m holds k=kg*16+m*8+[0,8).
// k -> block = ((k>>3)&1)*4 + (k>>4);  short idx = (block*64 + c)*8 + (k&7).
// Zero-filled past K (including whole pad tiles).  [validated R5-R8]
__global__ __launch_bounds__(256) void pack_w(BagArgs args,
                                              unsigned short* __restrict__ Wp) {
    __shared__ unsigned short ls[4][4096];
    const int wv = threadIdx.x >> 6;
    const int c  = threadIdx.x & 63;
    const int gtile = blockIdx.x * 4 + wv;

    int bag = 0;
#pragma unroll
    for (int b = 1; b < NBAGS; ++b)
        if (gtile >= args.tstart[b]) bag = b;
    const int lt = gtile - args.tstart[bag];
    const float* __restrict__ W = args.W[bag];
    const int K = args.K[bag];

    unsigned short* L = ls[wv];
#pragma unroll 8
    for (int k = 0; k < 64; ++k) {
        const int gk = lt * 64 + k;
        float v = (gk < K) ? W[(size_t)gk * LF + c] : 0.f;
        const int block = ((k >> 3) & 1) * 4 + (k >> 4);
        L[(block * LF + c) * 8 + (k & 7)] = f2bf(v);
    }
    __syncthreads();
    unsigned short* dst = Wp + ((size_t)gtile << 12);
#pragma unroll
    for (int j = 0; j < 8; ++j)
        *(short8*)(dst + c * 8 + j * 512) = *(const short8*)(L + c * 8 + j * 512);
}

// Fused stage+GEMM. Block = 128 rows x 1024 k. Stage: copy-shaped wave reads
// (one row's 1 KB per instruction = single DRAM page), bits packed into LDS
// (XOR-swizzled words). One barrier. Compute: 16 supersteps of MFMA with
// in-register bit->bf16 expansion; B from packed Wp; popcounts via ones-MFMA.
__global__ __launch_bounds__(256, 4) void bag_gemm(BagArgs args,
                                                   const unsigned short* __restrict__ Wp,
                                                   float* __restrict__ part,
                                                   float* __restrict__ sums)
{
    __shared__ unsigned bits[128 * 32];   // [row][word], word swizzled: w ^ (row&31)

    const int tid  = threadIdx.x;
    const int wave = tid >> 6;
    const int lane = tid & 63;
    const int fr   = lane & 15;
    const int kg   = lane >> 4;

    const int g  = blockIdx.x >> 4;    // global KC-chunk (bags 1..4)
    const int mt = blockIdx.x & 15;    // m-tile (128 rows)

    int bag = 1;
#pragma unroll
    for (int b = 2; b < NBAGS; ++b)
        if (g >= args.cstart[b]) bag = b;
    const int chunk = g - args.cstart[bag];
    const int K     = args.K[bag];
    const int kc0   = chunk * KC;
    const int row0b = mt * 128;
    const int row0w = wave * 32;       // wave's rows within block
    const int* __restrict__ Abase = args.A[bag];

    // ---------------- stage: 32 rows/wave, 4 x 1KB instrs per row ----------
    for (int it = 0; it < 16; ++it) {
        const int rr = row0w + it * 2;                 // 2 rows per iteration
        int4 v[8];
#pragma unroll
        for (int q = 0; q < 8; ++q) {
            const int row = row0b + rr + (q >> 2);
            const int col = kc0 + (q & 3) * 256 + lane * 4;
            const int* p = Abase + (size_t)row * K + min(col, K - 4);
            const int4 z = make_int4(0, 0, 0, 0);
            v[q] = (col < K) ? *(const int4*)p : z;
        }
#pragma unroll
        for (int q = 0; q < 8; ++q) {
            // ints are exactly {0,1}  [validated R7/R8]
            unsigned u = (unsigned)(v[q].x | (v[q].y << 1) | (v[q].z << 2) | (v[q].w << 3))
                         << ((lane & 7) * 4);
            u |= __shfl_xor(u, 1);
            u |= __shfl_xor(u, 2);
            u |= __shfl_xor(u, 4);
            if ((lane & 7) == 0) {
                const int row = rr + (q >> 2);         // local row 0..127
                const int w   = (q & 3) * 8 + (lane >> 3);
                bits[row * 32 + (w ^ (row & 31))] = u;
            }
        }
    }
    __syncthreads();

    // ---------------- compute: 16 supersteps of 64 k -----------------------
    const unsigned short* __restrict__ pB =
        Wp + ((size_t)(args.tstart[bag] + chunk * 16) << 12) + (kg * LF + fr) * 8;

    f32x4 acc0[4], acc1[4];
#pragma unroll
    for (int i = 0; i < 4; ++i) {
        acc0[i] = (f32x4){0.f, 0.f, 0.f, 0.f};
        acc1[i] = (f32x4){0.f, 0.f, 0.f, 0.f};
    }
    f32x4 accS0 = (f32x4){0.f, 0.f, 0.f, 0.f};
    f32x4 accS1 = (f32x4){0.f, 0.f, 0.f, 0.f};
    const int4 uo = make_int4(0x3F803F80, 0x3F803F80, 0x3F803F80, 0x3F803F80);
    const short8 ones = *(const short8*)&uo;

    // 2 bits -> dword of 2 bf16 (0x3F80 = bf16(1))   [validated R7/R8]
    auto bf16pair = [](unsigned b) -> int {
        return (int)((b & 1u) * 0x3F80u + (b & 2u) * 0x1FC00000u);
    };
    auto mkfrag = [&](unsigned byte) -> short8 {
        int4 u = make_int4(bf16pair(byte), bf16pair(byte >> 2),
                           bf16pair(byte >> 4), bf16pair(byte >> 6));
        return *(short8*)&u;
    };

    for (int ss = 0; ss < 16; ++ss) {
        const unsigned short* p = pB + (size_t)ss * 4096;
        short8 y[2][4];
#pragma unroll
        for (int m = 0; m < 2; ++m)
#pragma unroll
            for (int ni = 0; ni < 4; ++ni)
                y[m][ni] = *(const short8*)(p + m * 2048 + ni * 128);

        // A bits: word 2ss+(kg>>1) of rows row0w+fr (rowset0) and +16 (rowset1)
        const int wi = 2 * ss + (kg >> 1);
        const unsigned wrd0 = bits[(row0w + fr) * 32 + (wi ^ fr)];
        const unsigned wrd1 = bits[(row0w + 16 + fr) * 32 + (wi ^ (fr + 16))];

#pragma unroll
        for (int m = 0; m < 2; ++m) {
            const int sh = (kg & 1) * 16 + m * 8;
            const short8 fa0 = mkfrag((wrd0 >> sh) & 0xFFu);
            const short8 fa1 = mkfrag((wrd1 >> sh) & 0xFFu);
            accS0 = __builtin_amdgcn_mfma_f32_16x16x32_bf16(fa0, ones, accS0, 0, 0, 0);
            accS1 = __builtin_amdgcn_mfma_f32_16x16x32_bf16(fa1, ones, accS1, 0, 0, 0);
#pragma unroll
            for (int ni = 0; ni < 4; ++ni) {
                acc0[ni] = __builtin_amdgcn_mfma_f32_16x16x32_bf16(fa0, y[m][ni], acc0[ni], 0, 0, 0);
                acc1[ni] = __builtin_amdgcn_mfma_f32_16x16x32_bf16(fa1, y[m][ni], acc1[ni], 0, 0, 0);
            }
        }
    }

    // row popcounts from ones-MFMA: lane (fr,kg) reg r = rowsum of local row
    // kg*4+r (rowset0) / 16+kg*4+r (rowset1); all fr identical. [validated R5]
    if (fr == 0) {
#pragma unroll
        for (int r = 0; r < 4; ++r) {
            atomicAdd(&sums[bag * BROWS + row0b + row0w + kg * 4 + r],      accS0[r]);
            atomicAdd(&sums[bag * BROWS + row0b + row0w + 16 + kg * 4 + r], accS1[r]);
        }
    }

    // C/D: col = lane&15 (=fr), row = kg*4 + reg   [validated R1-R8]
    float* dst = part + ((size_t)g * BROWS + row0b + row0w + kg * 4) * LF + fr;
#pragma unroll
    for (int ni = 0; ni < 4; ++ni)
#pragma unroll
        for (int r = 0; r < 4; ++r) {
            dst[(size_t)(r) * LF + ni * 16]      = acc0[ni][r];
            dst[(size_t)(16 + r) * LF + ni * 16] = acc1[ni][r];
        }
}

// Sum split-K partials, normalize (incl. faithful "decades divided twice"
// bug), and compute the tiny K=12 decades bag directly in f32.
__global__ __launch_bounds__(256) void reduce_norm(BagArgs args,
                                                   const float* __restrict__ part,
                                                   float* __restrict__ out,
                                                   const float* __restrict__ sums)
{
    const int idx = blockIdx.x * 256 + threadIdx.x;
    if (idx >= BROWS * OUTC) return;
    const int row = idx / OUTC;
    const int c   = idx - row * OUTC;
    const int bag = c >> 6;
    const int col = c & 63;

    float v;
    if (bag == 0) {
        const int*   A0 = args.A[0];
        const float* W0 = args.W[0];
        float a = 0.f; int s = 0;
#pragma unroll
        for (int k = 0; k < 12; ++k) {
            const int x = A0[row * 12 + k];
            s += x;
            if (x) a += W0[k * LF + col];
        }
        if (s) a /= (float)s;
        const float sm = sums[1 * BROWS + row];   // ref bug: also divide by movie sum
        if (sm != 0.f) a /= sm;
        v = a;
    } else {
        float a = 0.f;
        for (int gg = args.cstart[bag]; gg < args.cstart[bag + 1]; ++gg)
            a += part[((size_t)gg * BROWS + row) * LF + col];
        v = a;
        if (bag >= 2) {
            const float s = sums[bag * BROWS + row];
            if (s != 0.f) v /= s;
        }
        // bag 1 (movies): never normalized (faithful to reference bug)
    }
    out[idx] = v;
}

// Correctness-only fallback (tiny ws): one thread per output element.
__global__ void naive_bag(BagArgs args, float* __restrict__ out) {
    const int row = blockIdx.x;
    const int c   = threadIdx.x;
    if (c >= OUTC) return;
    const int bag = c >> 6;
    const int col = c & 63;
    const int K = args.K[bag];
    const int* A = args.A[bag] + (size_t)row * K;
    const float* W = args.W[bag];
    float a = 0.f; int s = 0;
    for (int k = 0; k < K; ++k) {
        const int x = A[k];
        s += x;
        if (x) a += W[(size_t)k * LF + col];
    }
    if (bag != 1 && s) a /= (float)s;
    if (bag == 0) {
        const int* A1 = args.A[1] + (size_t)row * args.K[1];
        int sm = 0;
        for (int k = 0; k < args.K[1]; ++k) sm += A1[k];
        if (sm) a /= (float)sm;
    }
    out[(size_t)row * OUTC + c] = a;
}

extern "C" void kernel_launch(void* const* d_in, const int* in_sizes, int n_in,
                              void* d_out, int out_size, void* d_ws, size_t ws_size,
                              hipStream_t stream) {
    float* out = (float*)d_out;
    float* sums = (float*)d_ws;
    unsigned short* Wp = (unsigned short*)((char*)d_ws + WS_HEAD);
    float* part = (float*)((char*)d_ws + PART_OFF);

    BagArgs args;
    const int Ks[NBAGS] = {12, 60000, 32, 100000, 20000};
    int tcum = 0;
    for (int b = 0; b < NBAGS; ++b) {
        args.A[b] = (const int*)d_in[b];
        args.W[b] = (const float*)d_in[5 + b];
        args.K[b] = Ks[b];
        args.tstart[b] = tcum;
        tcum += ((Ks[b] + KC - 1) / KC) * 16;   // padded: 16+944+16+1568+320 = 2864
    }
    args.tstart[NBAGS] = tcum;
    args.cstart[0] = 0;
    int ccum = 0;
    for (int b = 1; b < NBAGS; ++b) {
        args.cstart[b] = ccum;
        ccum += (Ks[b] + KC - 1) / KC;          // 59 + 1 + 98 + 20 = 178
    }
    args.cstart[NBAGS] = ccum;

    const bool ok = ws_size >= PART_OFF + PART_BYTES;
    if (!ok) {
        naive_bag<<<BROWS, OUTC, 0, stream>>>(args, out);
        return;
    }

    hipMemsetAsync(sums, 0, NBAGS * BROWS * sizeof(float), stream);

    pack_w<<<tcum / 4, 256, 0, stream>>>(args, Wp);
    bag_gemm<<<NCHUNKS * NMT, 256, 0, stream>>>(args, Wp, part, sums);
    reduce_norm<<<(BROWS * OUTC + 255) / 256, 256, 0, stream>>>(args, part, out, sums);
}

// Round 10
// 460.792 us; speedup vs baseline: 1.2796x; 1.2573x over previous
//
#include <hip/hip_runtime.h>
#include <hip/hip_bf16.h>

#define LF 64
#define NBAGS 5
#define BROWS 2048
#define OUTC 320
#define KC 2048
#define NMT 16
#define NCHUNKS 90                 // bags 1..4: 30 + 1 + 49 + 10

#define WS_HEAD 65536
#define WP_BYTES 23068672ull       // 2816 tiles * 8192 B
#define BM_OFF (WS_HEAD + WP_BYTES)
#define BM_BYTES 46088192ull       // 2048 * 180032 / 8
#define PART_OFF (BM_OFF + BM_BYTES)
#define PART_BYTES ((size_t)NCHUNKS * BROWS * LF * 4)

typedef __attribute__((ext_vector_type(8))) short short8;
typedef __attribute__((ext_vector_type(4))) float f32x4;
typedef unsigned long long u64;

struct BagArgs {
    const int*   A[NBAGS];
    const float* W[NBAGS];
    int K[NBAGS];
    int cstart[NBAGS + 1];   // KC-chunk prefix, bags 1..4
    int tstart[NBAGS + 1];   // 64-k tile prefix, all bags
    long long bmoff[NBAGS];  // bitmask byte offset per bag
    int rsb[NBAGS];          // bitmask row stride, bytes (K/8)
};

__device__ __forceinline__ unsigned short f2bf(float f) {
    unsigned u = __float_as_uint(f);
    u += 0x7FFFu + ((u >> 16) & 1u);   // round-to-nearest-even
    return (unsigned short)(u >> 16);
}

// Pack W (f32 [K][64]) -> bf16 tiles of 64 k (8 KB), permuted so the B
// fragment matches A frags where lane (fr,kg), frag m holds k=kg*16+m*8+[0,8).
// k -> block = ((k>>3)&1)*4 + (k>>4);  short idx = (block*64 + c)*8 + (k&7).
// Zero-filled past K.  [validated R5-R9]
__global__ __launch_bounds__(256) void pack_w(BagArgs args,
                                              unsigned short* __restrict__ Wp) {
    __shared__ unsigned short ls[4][4096];
    const int wv = threadIdx.x >> 6;
    const int c  = threadIdx.x & 63;
    const int gtile = blockIdx.x * 4 + wv;

    int bag = 0;
#pragma unroll
    for (int b = 1; b < NBAGS; ++b)
        if (gtile >= args.tstart[b]) bag = b;
    const int lt = gtile - args.tstart[bag];
    const float* __restrict__ W = args.W[bag];
    const int K = args.K[bag];

    unsigned short* L = ls[wv];
#pragma unroll 8
    for (int k = 0; k < 64; ++k) {
        const int gk = lt * 64 + k;
        float v = (gk < K) ? W[(size_t)gk * LF + c] : 0.f;
        const int block = ((k >> 3) & 1) * 4 + (k >> 4);
        L[(block * LF + c) * 8 + (k & 7)] = f2bf(v);
    }
    __syncthreads();
    unsigned short* dst = Wp + ((size_t)gtile << 12);
#pragma unroll
    for (int j = 0; j < 8; ++j)
        *(short8*)(dst + c * 8 + j * 512) = *(const short8*)(L + c * 8 + j * 512);
}

// Pass 1: maximally fill-shaped read. Grid-stride monotone; wave covers 256
// ints per iter as 4 coalesced dword loads (lane L reads A[w0 + j*64 + L]);
// __ballot packs 64 bits per component (bit L == lane L == flat order);
// 4 lanes store 32 B contiguous. No LDS, no shfl, ~12 VGPR.
__global__ __launch_bounds__(256) void compress(const int* __restrict__ A,
                                                u64* __restrict__ bmw,
                                                long long n) {
    const int lane = threadIdx.x & 63;
    const long long stride = (long long)gridDim.x * 1024;
    long long w0 = ((long long)blockIdx.x * 4 + (threadIdx.x >> 6)) * 256;
    for (; w0 < n; w0 += stride) {
        const int* p = A + w0 + lane;
        const int v0 = p[0], v1 = p[64], v2 = p[128], v3 = p[192];
        const u64 b0 = __ballot(v0);
        const u64 b1 = __ballot(v1);
        const u64 b2 = __ballot(v2);
        const u64 b3 = __ballot(v3);
        if (lane < 4) {
            const u64 b = lane == 0 ? b0 : lane == 1 ? b1 : lane == 2 ? b2 : b3;
            bmw[(w0 >> 6) + lane] = b;
        }
    }
}

// Pass 2: MFMA GEMM off the flat bitmask. A = two masked u16 loads per lane
// per superstep (L3-resident); B = packed Wp fragments; R4's validated
// ping-pong + sched_barrier; popcounts via __popc + validated shfl-fold.
__global__ __launch_bounds__(256) void bag_gemm(BagArgs args,
                                                const unsigned short* __restrict__ Wp,
                                                const unsigned char* __restrict__ bm,
                                                float* __restrict__ part,
                                                int* __restrict__ sums)
{
    const int tid  = threadIdx.x;
    const int wave = tid >> 6;
    const int lane = tid & 63;
    const int fr   = lane & 15;
    const int kg   = lane >> 4;

    const int g  = blockIdx.x >> 4;
    const int mt = blockIdx.x & 15;

    int bag = 1;
#pragma unroll
    for (int b = 2; b < NBAGS; ++b)
        if (g >= args.cstart[b]) bag = b;
    const int chunk  = g - args.cstart[bag];
    const int K      = args.K[bag];
    const int kc0    = chunk * KC;
    const int nsuper = (min(kc0 + KC, K) - kc0 + 63) >> 6;
    const int rsb    = args.rsb[bag];

    const int row0 = mt * 128 + wave * 32;
    const unsigned short* __restrict__ pb0 = (const unsigned short*)
        (bm + args.bmoff[bag] + (size_t)(row0 + fr) * rsb + (kc0 >> 3));
    const unsigned short* __restrict__ pb1 = (const unsigned short*)
        ((const unsigned char*)pb0 + (size_t)16 * rsb);
    const unsigned short* __restrict__ pB =
        Wp + ((size_t)(args.tstart[bag] + chunk * (KC / 64)) << 12) + (kg * LF + fr) * 8;

    f32x4 acc0[4], acc1[4];
#pragma unroll
    for (int i = 0; i < 4; ++i) {
        acc0[i] = (f32x4){0.f, 0.f, 0.f, 0.f};
        acc1[i] = (f32x4){0.f, 0.f, 0.f, 0.f};
    }
    int psum0 = 0, psum1 = 0;

    auto loadA = [&](int ss, unsigned& x0, unsigned& x1) {
        const int k0 = kc0 + ss * 64 + kg * 16;
        x0 = 0; x1 = 0;
        if (k0 < K) {                       // K%16==0: u16 fully in/out of row
            x0 = pb0[ss * 4 + kg];
            x1 = pb1[ss * 4 + kg];
        }
    };
    auto loadB = [&](int ss, short8 (&y)[2][4]) {
        const unsigned short* p = pB + (size_t)ss * 4096;
#pragma unroll
        for (int m = 0; m < 2; ++m)
#pragma unroll
            for (int ni = 0; ni < 4; ++ni)
                y[m][ni] = *(const short8*)(p + m * 2048 + ni * 128);
    };

    // 2 bits -> dword of 2 bf16 (0x3F80 = bf16(1))   [validated R7-R9]
    auto bf16pair = [](unsigned b) -> int {
        return (int)((b & 1u) * 0x3F80u + (b & 2u) * 0x1FC00000u);
    };
    auto mkfrag = [&](unsigned byte) -> short8 {
        int4 u = make_int4(bf16pair(byte), bf16pair(byte >> 2),
                           bf16pair(byte >> 4), bf16pair(byte >> 6));
        return *(short8*)&u;
    };
    auto compute = [&](unsigned x0, unsigned x1, const short8 (&y)[2][4]) {
        psum0 += __popc(x0);
        psum1 += __popc(x1);
#pragma unroll
        for (int m = 0; m < 2; ++m) {
            const short8 fa0 = mkfrag((x0 >> (m * 8)) & 0xFFu);
            const short8 fa1 = mkfrag((x1 >> (m * 8)) & 0xFFu);
#pragma unroll
            for (int ni = 0; ni < 4; ++ni) {
                acc0[ni] = __builtin_amdgcn_mfma_f32_16x16x32_bf16(fa0, y[m][ni], acc0[ni], 0, 0, 0);
                acc1[ni] = __builtin_amdgcn_mfma_f32_16x16x32_bf16(fa1, y[m][ni], acc1[ni], 0, 0, 0);
            }
        }
    };

    unsigned Aa0, Aa1, Ab0, Ab1;
    short8 Ba[2][4], Bb[2][4];
    loadA(0, Aa0, Aa1);
    loadB(0, Ba);
    const int npair = (nsuper + 1) >> 1;
    for (int p = 0; p < npair; ++p) {
        const int s1  = 2 * p + 1;
        const int s1c = min(s1, nsuper - 1);
        loadA(s1c, Ab0, Ab1);
        loadB(s1c, Bb);
        __builtin_amdgcn_sched_barrier(0);
        compute(Aa0, Aa1, Ba);                  // step 2p (always valid)
        const int s2c = min(2 * p + 2, nsuper - 1);
        loadA(s2c, Aa0, Aa1);
        loadB(s2c, Ba);
        __builtin_amdgcn_sched_barrier(0);
        if (s1 < nsuper)                        // uniform pad guard
            compute(Ab0, Ab1, Bb);
    }

    // fold kg slices (lanes fr, fr+16, fr+32, fr+48)   [validated R4]
    psum0 += __shfl_xor(psum0, 16);
    psum0 += __shfl_xor(psum0, 32);
    psum1 += __shfl_xor(psum1, 16);
    psum1 += __shfl_xor(psum1, 32);
    if (kg == 0) {
        atomicAdd(&sums[bag * BROWS + row0 + fr], psum0);
        atomicAdd(&sums[bag * BROWS + row0 + 16 + fr], psum1);
    }

    // C/D: col = lane&15 (=fr), row = kg*4 + reg   [validated R1-R9]
    float* dst = part + ((size_t)g * BROWS + row0 + kg * 4) * LF + fr;
#pragma unroll
    for (int ni = 0; ni < 4; ++ni)
#pragma unroll
        for (int r = 0; r < 4; ++r) {
            dst[(size_t)(r) * LF + ni * 16]      = acc0[ni][r];
            dst[(size_t)(16 + r) * LF + ni * 16] = acc1[ni][r];
        }
}

// Sum split-K partials, normalize (incl. faithful "decades divided twice"
// bug), and compute the tiny K=12 decades bag directly in f32.
__global__ __launch_bounds__(256) void reduce_norm(BagArgs args,
                                                   const float* __restrict__ part,
                                                   float* __restrict__ out,
                                                   const int* __restrict__ sums)
{
    const int idx = blockIdx.x * 256 + threadIdx.x;
    if (idx >= BROWS * OUTC) return;
    const int row = idx / OUTC;
    const int c   = idx - row * OUTC;
    const int bag = c >> 6;
    const int col = c & 63;

    float v;
    if (bag == 0) {
        const int*   A0 = args.A[0];
        const float* W0 = args.W[0];
        float a = 0.f; int s = 0;
#pragma unroll
        for (int k = 0; k < 12; ++k) {
            const int x = A0[row * 12 + k];
            s += x;
            if (x) a += W0[k * LF + col];
        }
        if (s) a /= (float)s;
        const int sm = sums[1 * BROWS + row];   // ref bug: also divide by movie sum
        if (sm) a /= (float)sm;
        v = a;
    } else {
        float a = 0.f;
        for (int gg = args.cstart[bag]; gg < args.cstart[bag + 1]; ++gg)
            a += part[((size_t)gg * BROWS + row) * LF + col];
        v = a;
        if (bag >= 2) {
            const int s = sums[bag * BROWS + row];
            if (s) v /= (float)s;
        }
        // bag 1 (movies): never normalized (faithful to reference bug)
    }
    out[idx] = v;
}

// Correctness-only fallback (tiny ws): one thread per output element.
__global__ void naive_bag(BagArgs args, float* __restrict__ out) {
    const int row = blockIdx.x;
    const int c   = threadIdx.x;
    if (c >= OUTC) return;
    const int bag = c >> 6;
    const int col = c & 63;
    const int K = args.K[bag];
    const int* A = args.A[bag] + (size_t)row * K;
    const float* W = args.W[bag];
    float a = 0.f; int s = 0;
    for (int k = 0; k < K; ++k) {
        const int x = A[k];
        s += x;
        if (x) a += W[(size_t)k * LF + col];
    }
    if (bag != 1 && s) a /= (float)s;
    if (bag == 0) {
        const int* A1 = args.A[1] + (size_t)row * args.K[1];
        int sm = 0;
        for (int k = 0; k < args.K[1]; ++k) sm += A1[k];
        if (sm) a /= (float)sm;
    }
    out[(size_t)row * OUTC + c] = a;
}

extern "C" void kernel_launch(void* const* d_in, const int* in_sizes, int n_in,
                              void* d_out, int out_size, void* d_ws, size_t ws_size,
                              hipStream_t stream) {
    float* out = (float*)d_out;
    int* sums = (int*)d_ws;
    unsigned short* Wp = (unsigned short*)((char*)d_ws + WS_HEAD);
    unsigned char* bm  = (unsigned char*)((char*)d_ws + BM_OFF);
    float* part = (float*)((char*)d_ws + PART_OFF);

    BagArgs args;
    const int Ks[NBAGS] = {12, 60000, 32, 100000, 20000};
    int tcum = 0;
    for (int b = 0; b < NBAGS; ++b) {
        args.A[b] = (const int*)d_in[b];
        args.W[b] = (const float*)d_in[5 + b];
        args.K[b] = Ks[b];
        args.tstart[b] = tcum;
        tcum += (Ks[b] + 63) / 64;          // -> 2816
    }
    args.tstart[NBAGS] = tcum;
    args.cstart[0] = 0;
    int ccum = 0;
    for (int b = 1; b < NBAGS; ++b) {
        args.cstart[b] = ccum;
        ccum += (Ks[b] + KC - 1) / KC;      // 30 + 1 + 49 + 10 = 90
    }
    args.cstart[NBAGS] = ccum;

    // flat bitmask geometry (bit i of bag b == A_b_flat[i])
    args.rsb[0] = 0; args.bmoff[0] = 0;
    long long bcum = 0;
    for (int b = 1; b < NBAGS; ++b) {
        args.rsb[b] = Ks[b] / 8;            // 7500, 4, 12500, 2500
        args.bmoff[b] = bcum;
        bcum += (long long)BROWS * args.rsb[b];
    }

    const bool ok = ws_size >= PART_OFF + PART_BYTES;
    if (!ok) {
        naive_bag<<<BROWS, OUTC, 0, stream>>>(args, out);
        return;
    }

    hipMemsetAsync(sums, 0, NBAGS * BROWS * sizeof(int), stream);

    pack_w<<<tcum / 4, 256, 0, stream>>>(args, Wp);
    for (int b = 1; b < NBAGS; ++b) {
        const long long n = (long long)BROWS * Ks[b];    // n % 1024 == 0
        const int nb = (int)((n / 1024 < 2048) ? n / 1024 : 2048);
        compress<<<nb, 256, 0, stream>>>(args.A[b], (u64*)(bm + args.bmoff[b]), n);
    }
    bag_gemm<<<NCHUNKS * NMT, 256, 0, stream>>>(args, Wp, bm, part, sums);
    reduce_norm<<<(BROWS * OUTC + 255) / 256, 256, 0, stream>>>(args, part, out, sums);
}

// Round 11
// 435.438 us; speedup vs baseline: 1.3541x; 1.0582x over previous
//
#include <hip/hip_runtime.h>
#include <hip/hip_bf16.h>

#define LF 64
#define NBAGS 5
#define BROWS 2048
#define OUTC 320
#define KC 2048
#define NMT 16
#define NCHUNKS 90                 // bags 1..4: 30 + 1 + 49 + 10
#define NSLOTX 45                  // 180 padded 1024-bit windows / 4 waves

#define WS_HEAD 65536
#define NTILES 2912                // 32 tiles per padded chunk, bags 0..4
#define WP_BYTES ((size_t)NTILES * 8192)
#define BM_OFF (WS_HEAD + WP_BYTES)
#define BM_BYTES ((size_t)BROWS * 23040)            // 47,185,920
#define PART_OFF (BM_OFF + BM_BYTES)
#define PART_BYTES ((size_t)NCHUNKS * BROWS * LF * 4)

typedef __attribute__((ext_vector_type(8))) short short8;
typedef __attribute__((ext_vector_type(4))) float f32x4;

struct BagArgs {
    const int*   A[NBAGS];
    const float* W[NBAGS];
    int K[NBAGS];
    int cstart[NBAGS + 1];   // KC-chunk prefix, bags 1..4
    int tstart[NBAGS + 1];   // 64-k tile prefix (32 per padded chunk)
    long long bmoff[NBAGS];  // bitmask byte offset per bag
    int rsp[NBAGS];          // padded bitmask row stride, bytes (nch*256)
};

__device__ __forceinline__ unsigned short f2bf(float f) {
    unsigned u = __float_as_uint(f);
    u += 0x7FFFu + ((u >> 16) & 1u);   // round-to-nearest-even
    return (unsigned short)(u >> 16);
}

// Pack W (f32 [K][64]) -> bf16 tiles of 64 k (8 KB), permuted so the B
// fragment matches A frags where lane (fr,kg), frag m holds k=kg*16+m*8+[0,8).
// k -> block = ((k>>3)&1)*4 + (k>>4);  short idx = (block*64 + c)*8 + (k&7).
// Zero-filled past K (incl. whole pad tiles).  [validated R5-R10]
__global__ __launch_bounds__(256) void pack_w(BagArgs args,
                                              unsigned short* __restrict__ Wp) {
    __shared__ unsigned short ls[4][4096];
    const int wv = threadIdx.x >> 6;
    const int c  = threadIdx.x & 63;
    const int gtile = blockIdx.x * 4 + wv;

    int bag = 0;
#pragma unroll
    for (int b = 1; b < NBAGS; ++b)
        if (gtile >= args.tstart[b]) bag = b;
    const int lt = gtile - args.tstart[bag];
    const float* __restrict__ W = args.W[bag];
    const int K = args.K[bag];

    unsigned short* L = ls[wv];
#pragma unroll 8
    for (int k = 0; k < 64; ++k) {
        const int gk = lt * 64 + k;          // plain k coordinate (pad -> 0)
        float v = (gk < K) ? W[(size_t)gk * LF + c] : 0.f;
        const int block = ((k >> 3) & 1) * 4 + (k >> 4);
        L[(block * LF + c) * 8 + (k & 7)] = f2bf(v);
    }
    __syncthreads();
    unsigned short* dst = Wp + ((size_t)gtile << 12);
#pragma unroll
    for (int j = 0; j < 8; ++j)
        *(short8*)(dst + c * 8 + j * 512) = *(const short8*)(L + c * 8 + j * 512);
}

// Pass 1: fill-shaped compress. Wave = one 1024-k window of one row: 4 x 1KB
// coalesced loads (issued together), validated nibble+shfl pack, 32 B
// contiguous store per step (128 B per window). Rows padded with zero bits
// to 256 B per 2048-k chunk, so the GEMM needs no masking anywhere.
__global__ __launch_bounds__(256) void compress(BagArgs args,
                                                unsigned char* __restrict__ bm) {
    const int lane = threadIdx.x & 63;
    const int slot = blockIdx.x * 4 + (threadIdx.x >> 6);   // 0..179
    int bag, s0;
    if      (slot >= 160) { bag = 4; s0 = 160; }
    else if (slot >=  62) { bag = 3; s0 = 62;  }
    else if (slot >=  60) { bag = 2; s0 = 60;  }
    else                  { bag = 1; s0 = 0;   }
    const int w   = slot - s0;
    const int row = blockIdx.y;
    const int K   = args.K[bag];
    const int* __restrict__ A = args.A[bag] + (size_t)row * K;
    unsigned char* __restrict__ dst =
        bm + args.bmoff[bag] + (size_t)row * args.rsp[bag] + w * 128;

    int4 vv[4];
#pragma unroll
    for (int s = 0; s < 4; ++s) {
        const int col = w * 1024 + s * 256 + lane * 4;   // K%4==0
        vv[s] = make_int4(0, 0, 0, 0);
        if (col < K) vv[s] = *(const int4*)(A + col);
    }
#pragma unroll
    for (int s = 0; s < 4; ++s) {
        const int4 v = vv[s];
        // ints are exactly {0,1}  [validated R7-R10]
        unsigned u = (unsigned)(v.x | (v.y << 1) | (v.z << 2) | (v.w << 3))
                     << ((lane & 7) * 4);
        u |= __shfl_xor(u, 1);
        u |= __shfl_xor(u, 2);
        u |= __shfl_xor(u, 4);
        if ((lane & 7) == 0)
            *(unsigned*)(dst + s * 32 + (lane >> 3) * 4) = u;
    }
}

// Pass 2: MFMA GEMM off the padded bitmask. Stage: 32 KB of bm per block via
// fully-coalesced 1 KB wave reads -> LDS (quad-XOR swizzle). Compute: 32
// uniform supersteps; A from ds_read_b32 + validated mkfrag; B ping-ponged
// from packed Wp; popcounts via validated ones-MFMA. No masking, no tails.
__global__ __launch_bounds__(256) void bag_gemm(BagArgs args,
                                                const unsigned short* __restrict__ Wp,
                                                const unsigned char* __restrict__ bm,
                                                float* __restrict__ part,
                                                float* __restrict__ sums)
{
    __shared__ unsigned bits[128 * 64];   // [row][word], quad-swizzled: 32 KB

    const int tid  = threadIdx.x;
    const int wave = tid >> 6;
    const int lane = tid & 63;
    const int fr   = lane & 15;
    const int kg   = lane >> 4;

    const int g  = blockIdx.x >> 4;    // global chunk (bags 1..4)
    const int mt = blockIdx.x & 15;    // m-tile (128 rows)

    int bag = 1;
#pragma unroll
    for (int b = 2; b < NBAGS; ++b)
        if (g >= args.cstart[b]) bag = b;
    const int chunk = g - args.cstart[bag];
    const int row0b = mt * 128;

    // ---- stage: wave reads 32 rows x 256 B, 8 instrs of 1 KB coalesced ----
    {
        const unsigned char* srcb = bm + args.bmoff[bag] + chunk * 256
                                  + (size_t)row0b * args.rsp[bag];
#pragma unroll
        for (int it = 0; it < 8; ++it) {
            const int lrow = wave * 32 + it * 4 + (lane >> 4);
            const uint4 v = *(const uint4*)(srcb + (size_t)lrow * args.rsp[bag]
                                            + (lane & 15) * 16);
            const int sq = (lane & 15) ^ (lrow & 15);
            *(uint4*)&bits[lrow * 64 + sq * 4] = v;
        }
    }
    __syncthreads();

    // ---- compute ----------------------------------------------------------
    const unsigned short* __restrict__ pB =
        Wp + ((size_t)(args.tstart[bag] + chunk * 32) << 12) + (kg * LF + fr) * 8;

    f32x4 acc0[4], acc1[4];
#pragma unroll
    for (int i = 0; i < 4; ++i) {
        acc0[i] = (f32x4){0.f, 0.f, 0.f, 0.f};
        acc1[i] = (f32x4){0.f, 0.f, 0.f, 0.f};
    }
    f32x4 accS0 = (f32x4){0.f, 0.f, 0.f, 0.f};
    f32x4 accS1 = (f32x4){0.f, 0.f, 0.f, 0.f};
    const int4 uo = make_int4(0x3F803F80, 0x3F803F80, 0x3F803F80, 0x3F803F80);
    const short8 ones = *(const short8*)&uo;

    auto loadB = [&](int ss, short8 (&y)[2][4]) {
        const unsigned short* p = pB + (size_t)ss * 4096;
#pragma unroll
        for (int m = 0; m < 2; ++m)
#pragma unroll
            for (int ni = 0; ni < 4; ++ni)
                y[m][ni] = *(const short8*)(p + m * 2048 + ni * 128);
    };
    // 2 bits -> dword of 2 bf16 (0x3F80 = bf16(1))   [validated R7-R10]
    auto bf16pair = [](unsigned b) -> int {
        return (int)((b & 1u) * 0x3F80u + (b & 2u) * 0x1FC00000u);
    };
    auto mkfrag = [&](unsigned byte) -> short8 {
        int4 u = make_int4(bf16pair(byte), bf16pair(byte >> 2),
                           bf16pair(byte >> 4), bf16pair(byte >> 6));
        return *(short8*)&u;
    };
    auto compute = [&](int ss, const short8 (&y)[2][4]) {
        const int wi = ss * 2 + (kg >> 1);
        const int wq = ((wi >> 2) ^ fr) * 4 + (wi & 3);
        const unsigned wrd0 = bits[(wave * 32 + fr) * 64 + wq];
        const unsigned wrd1 = bits[(wave * 32 + 16 + fr) * 64 + wq];
#pragma unroll
        for (int m = 0; m < 2; ++m) {
            const int sh = (kg & 1) * 16 + m * 8;      // [validated R9]
            const short8 fa0 = mkfrag((wrd0 >> sh) & 0xFFu);
            const short8 fa1 = mkfrag((wrd1 >> sh) & 0xFFu);
            accS0 = __builtin_amdgcn_mfma_f32_16x16x32_bf16(fa0, ones, accS0, 0, 0, 0);
            accS1 = __builtin_amdgcn_mfma_f32_16x16x32_bf16(fa1, ones, accS1, 0, 0, 0);
#pragma unroll
            for (int ni = 0; ni < 4; ++ni) {
                acc0[ni] = __builtin_amdgcn_mfma_f32_16x16x32_bf16(fa0, y[m][ni], acc0[ni], 0, 0, 0);
                acc1[ni] = __builtin_amdgcn_mfma_f32_16x16x32_bf16(fa1, y[m][ni], acc1[ni], 0, 0, 0);
            }
        }
    };

    short8 Ba[2][4], Bb[2][4];
    loadB(0, Ba);
#pragma unroll 1
    for (int p = 0; p < 16; ++p) {
        loadB(2 * p + 1, Bb);
        __builtin_amdgcn_sched_barrier(0);
        compute(2 * p, Ba);
        loadB(min(2 * p + 2, 31), Ba);
        __builtin_amdgcn_sched_barrier(0);
        compute(2 * p + 1, Bb);
    }

    // popcounts from ones-MFMA (exact in f32)   [validated R9]
    if (fr == 0) {
#pragma unroll
        for (int r = 0; r < 4; ++r) {
            atomicAdd(&sums[bag * BROWS + row0b + wave * 32 + kg * 4 + r],      accS0[r]);
            atomicAdd(&sums[bag * BROWS + row0b + wave * 32 + 16 + kg * 4 + r], accS1[r]);
        }
    }

    // C/D: col = lane&15 (=fr), row = kg*4 + reg   [validated R1-R10]
    float* dst = part + ((size_t)g * BROWS + row0b + wave * 32 + kg * 4) * LF + fr;
#pragma unroll
    for (int ni = 0; ni < 4; ++ni)
#pragma unroll
        for (int r = 0; r < 4; ++r) {
            dst[(size_t)(r) * LF + ni * 16]      = acc0[ni][r];
            dst[(size_t)(16 + r) * LF + ni * 16] = acc1[ni][r];
        }
}

// Sum split-K partials, normalize (incl. faithful "decades divided twice"
// bug), and compute the tiny K=12 decades bag directly in f32.
__global__ __launch_bounds__(256) void reduce_norm(BagArgs args,
                                                   const float* __restrict__ part,
                                                   float* __restrict__ out,
                                                   const float* __restrict__ sums)
{
    const int idx = blockIdx.x * 256 + threadIdx.x;
    if (idx >= BROWS * OUTC) return;
    const int row = idx / OUTC;
    const int c   = idx - row * OUTC;
    const int bag = c >> 6;
    const int col = c & 63;

    float v;
    if (bag == 0) {
        const int*   A0 = args.A[0];
        const float* W0 = args.W[0];
        float a = 0.f; int s = 0;
#pragma unroll
        for (int k = 0; k < 12; ++k) {
            const int x = A0[row * 12 + k];
            s += x;
            if (x) a += W0[k * LF + col];
        }
        if (s) a /= (float)s;
        const float sm = sums[1 * BROWS + row];   // ref bug: also divide by movie sum
        if (sm != 0.f) a /= sm;
        v = a;
    } else {
        float a = 0.f;
        for (int gg = args.cstart[bag]; gg < args.cstart[bag + 1]; ++gg)
            a += part[((size_t)gg * BROWS + row) * LF + col];
        v = a;
        if (bag >= 2) {
            const float s = sums[bag * BROWS + row];
            if (s != 0.f) v /= s;
        }
        // bag 1 (movies): never normalized (faithful to reference bug)
    }
    out[idx] = v;
}

// Correctness-only fallback (tiny ws): one thread per output element.
__global__ void naive_bag(BagArgs args, float* __restrict__ out) {
    const int row = blockIdx.x;
    const int c   = threadIdx.x;
    if (c >= OUTC) return;
    const int bag = c >> 6;
    const int col = c & 63;
    const int K = args.K[bag];
    const int* A = args.A[bag] + (size_t)row * K;
    const float* W = args.W[bag];
    float a = 0.f; int s = 0;
    for (int k = 0; k < K; ++k) {
        const int x = A[k];
        s += x;
        if (x) a += W[(size_t)k * LF + col];
    }
    if (bag != 1 && s) a /= (float)s;
    if (bag == 0) {
        const int* A1 = args.A[1] + (size_t)row * args.K[1];
        int sm = 0;
        for (int k = 0; k < args.K[1]; ++k) sm += A1[k];
        if (sm) a /= (float)sm;
    }
    out[(size_t)row * OUTC + c] = a;
}

extern "C" void kernel_launch(void* const* d_in, const int* in_sizes, int n_in,
                              void* d_out, int out_size, void* d_ws, size_t ws_size,
                              hipStream_t stream) {
    float* out = (float*)d_out;
    float* sums = (float*)d_ws;
    unsigned short* Wp = (unsigned short*)((char*)d_ws + WS_HEAD);
    unsigned char* bm  = (unsigned char*)((char*)d_ws + BM_OFF);
    float* part = (float*)((char*)d_ws + PART_OFF);

    BagArgs args;
    const int Ks[NBAGS] = {12, 60000, 32, 100000, 20000};
    int tcum = 0;
    for (int b = 0; b < NBAGS; ++b) {
        args.A[b] = (const int*)d_in[b];
        args.W[b] = (const float*)d_in[5 + b];
        args.K[b] = Ks[b];
        args.tstart[b] = tcum;
        tcum += ((Ks[b] + KC - 1) / KC) * 32;   // 32+960+32+1568+320 = 2912
    }
    args.tstart[NBAGS] = tcum;
    args.cstart[0] = 0;
    int ccum = 0;
    for (int b = 1; b < NBAGS; ++b) {
        args.cstart[b] = ccum;
        ccum += (Ks[b] + KC - 1) / KC;          // 30 + 1 + 49 + 10 = 90
    }
    args.cstart[NBAGS] = ccum;

    // padded bitmask: row stride = nch*256 B; zero bits fill pads
    args.rsp[0] = 0; args.bmoff[0] = 0;
    long long bcum = 0;
    for (int b = 1; b < NBAGS; ++b) {
        args.rsp[b] = ((Ks[b] + KC - 1) / KC) * 256;   // 7680,256,12544,2560
        args.bmoff[b] = bcum;
        bcum += (long long)BROWS * args.rsp[b];
    }

    const bool ok = ws_size >= PART_OFF + PART_BYTES;
    if (!ok) {
        naive_bag<<<BROWS, OUTC, 0, stream>>>(args, out);
        return;
    }

    hipMemsetAsync(sums, 0, NBAGS * BROWS * sizeof(float), stream);

    pack_w<<<tcum / 4, 256, 0, stream>>>(args, Wp);
    compress<<<dim3(NSLOTX, BROWS), 256, 0, stream>>>(args, bm);
    bag_gemm<<<NCHUNKS * NMT, 256, 0, stream>>>(args, Wp, bm, part, sums);
    reduce_norm<<<(BROWS * OUTC + 255) / 256, 256, 0, stream>>>(args, part, out, sums);
}